// Round 5
// baseline (464.814 us; speedup 1.0000x reference)
//
#include <hip/hip_runtime.h>

// SNU with bias-sign collapse:
//   y_t = (relu(xw_t + 0.8*h*(1-y)) + b > 0).  relu >= 0, so b_h > 0  =>  y == 1 for all t.
// Only columns with b_h <= 0 (~81 of 512) need the GEMM + sequential scan.
//
// R5: split-K x4 GEMM (2048 working blocks = 8/CU -> R1's 71%-VALU regime; R1-R4
// showed VALUBusy tracks resident blocks: 8/CU->71%, 4/CU->33%, 2/CU->25-30%).
// Scan sums the 4 partials inline. compact+gather fused into one dispatch.
//
// ws layout (bytes):
//   0       : int hdr[2] = {count, pc}
//   64      : int idx[256]        compacted h-indices (ascending, padded w/ idx[0])
//   4096    : float Wc[512][256]  gathered W columns (512 KB)
//   1<<20   : float xwp[4][T=512][B=128][128]   4 x 32 MB split-K partials, (t,b,j)
//   129<<20 : float xwc1[T=512][B=128][128]     overflow direct buffer (j in [128,256)),
//                                               touched only if count > 128 (P ~ 6e-9)

#define DECAYF 0.8f
#define PART   ((size_t)512 * 128 * 128)   // floats per split-K partial

// ---------- 1. compact columns with b <= 0, then gather Wc = W[:, idx] ----------
__global__ __launch_bounds__(512) void compact_gather(const float* __restrict__ bias,
                                                      const float* __restrict__ W,
                                                      int* __restrict__ hdr,
                                                      int* __restrict__ idx,
                                                      float* __restrict__ Wc) {
    __shared__ unsigned long long wmask[8];
    __shared__ int idx_s[256];
    const int tid = threadIdx.x;           // 512 threads, H=512
    const bool p = (bias[tid] <= 0.0f);
    unsigned long long m = __ballot(p);
    const int wid = tid >> 6, lane = tid & 63;
    if (lane == 0) wmask[wid] = m;
    __syncthreads();
    int before = 0, total = 0;
    #pragma unroll
    for (int w = 0; w < 8; w++) {
        int c = __popcll(wmask[w]);
        if (w < wid) before += c;
        total += c;
    }
    if (p) idx_s[before + __popcll(m & ((1ull << lane) - 1ull))] = tid;
    __syncthreads();
    int idx0 = (total > 0) ? idx_s[0] : 0;
    if (tid >= total && tid < 256) idx_s[tid] = idx0;    // pad
    __syncthreads();
    if (tid < 256) idx[tid] = idx_s[tid];
    if (tid == 0) {
        int pc = (total + 127) & ~127;
        if (pc < 128) pc = 128;
        if (pc > 256) pc = 256;                          // safety clamp (fits ws)
        hdr[0] = total;
        hdr[1] = pc;
    }
    // gather: thread (i0, j) copies rows i0, i0+2, ... of column idx_s[j]
    const int j  = tid & 255;
    const int i0 = tid >> 8;
    const int hsrc = idx_s[j];
    for (int i = i0; i < 512; i += 2)
        Wc[i * 256 + j] = W[i * 512 + hsrc];             // W is L2-resident (1 MB)
}

// ---------- 2. GEMM: x(B,I,T) x Wc(I,:) -> partials ----------
// grid (5, 4, 128) = (kc, t-tiles, B).  kc<4: split-K chunk of 128 over cols 0..127
// into xwp[kc]. kc==4: overflow path (full K, cols 128..255) -> xwc1; exits if pc<=128.
// 2048 working blocks -> ~8/CU. Inner loop identical to R1 (8x8/thread, 128x128 tile).
__global__ __launch_bounds__(256) void gemm_split(const float* __restrict__ x,
                                                  const float* __restrict__ Wc,
                                                  const int* __restrict__ hdr,
                                                  float* __restrict__ xwp,
                                                  float* __restrict__ xwc1) {
    const int kc = blockIdx.x;
    int kbeg, kend, coff;
    float* op;
    if (kc < 4) { kbeg = kc * 128; kend = kbeg + 128; coff = 0;   op = xwp + (size_t)kc * PART; }
    else        { if (hdr[1] <= 128) return;
                  kbeg = 0;        kend = 512;        coff = 128; op = xwc1; }
    const int I = 512, T = 512, NC = 256;
    const int b  = blockIdx.z;
    const int t0 = blockIdx.y * 128;

    __shared__ float As[16][132];  // [i][t]
    __shared__ float Bs[16][132];  // [i][j]

    const int tid  = threadIdx.x;
    const int wave = tid >> 6;
    const int lane = tid & 63;
    const int lx = lane & 7;
    const int ly = lane >> 3;
    const int m_base = ((wave >> 1) << 6) + ly * 8;  // t within tile (0..127)
    const int n_base = ((wave & 1) << 6) + lx * 8;   // j within 128 cols

    float acc[8][8];
    #pragma unroll
    for (int i = 0; i < 8; i++)
        #pragma unroll
        for (int j = 0; j < 8; j++) acc[i][j] = 0.f;

    const float* xb = x + (size_t)b * I * T;

    for (int k0 = kbeg; k0 < kend; k0 += 16) {
        #pragma unroll
        for (int j = 0; j < 2; j++) {   // stage 16x128 of A and B: 2 float4/thread each
            int id2 = tid + j * 256;
            int row = id2 >> 5;
            int c4  = (id2 & 31) << 2;
            *(float4*)&As[row][c4] = *(const float4*)(xb + (size_t)(k0 + row) * T + t0 + c4);
            *(float4*)&Bs[row][c4] = *(const float4*)(Wc + (size_t)(k0 + row) * NC + coff + c4);
        }
        __syncthreads();
        #pragma unroll
        for (int kk = 0; kk < 16; kk++) {
            float a[8], bb[8];
            *(float4*)&a[0]  = *(const float4*)&As[kk][m_base];
            *(float4*)&a[4]  = *(const float4*)&As[kk][m_base + 4];
            *(float4*)&bb[0] = *(const float4*)&Bs[kk][n_base];
            *(float4*)&bb[4] = *(const float4*)&Bs[kk][n_base + 4];
            #pragma unroll
            for (int mi = 0; mi < 8; mi++)
                #pragma unroll
                for (int ni = 0; ni < 8; ni++)
                    acc[mi][ni] = fmaf(a[mi], bb[ni], acc[mi][ni]);
        }
        __syncthreads();
    }

    // store (t,b,j) layout: per t, a wave covers 8 x 32B contiguous runs
    #pragma unroll
    for (int mi = 0; mi < 8; mi++) {
        int t = t0 + m_base + mi;
        float* o = op + ((size_t)t * 128 + b) * 128 + n_base;
        *(float4*)o       = *(float4*)&acc[mi][0];
        *(float4*)(o + 4) = *(float4*)&acc[mi][4];
    }
}

// ---------- 3. ones-fill: rows with bias > 0 are all-ones ----------
__global__ __launch_bounds__(256) void fill_ones(const float* __restrict__ bias,
                                                 float4* __restrict__ out4) {
    const float4 ones = make_float4(1.f, 1.f, 1.f, 1.f);
    const int base = blockIdx.x * 2048;
    #pragma unroll
    for (int q = 0; q < 8; q++) {
        int f4 = base + q * 256 + threadIdx.x;   // (B,H,T): 128 float4 per h-row
        int h = (f4 >> 7) & 511;
        if (bias[h] > 0.0f) out4[f4] = ones;
    }
}

// ---------- 4. scan: sum 4 partials inline, run recurrence, write spikes ----------
// grid (128 b, 2 jt) x 128 threads. jt=0: j<128 from xwp; jt=1: overflow from xwc1.
__global__ __launch_bounds__(128) void snu_scan(const float* __restrict__ xwp,
                                                const float* __restrict__ xwc1,
                                                const float* __restrict__ bias,
                                                const int* __restrict__ hdr,
                                                const int* __restrict__ idx,
                                                float* __restrict__ out) {
    const int T = 512;
    const int b  = blockIdx.x;
    const int jt = blockIdx.y;
    const int j  = jt * 128 + threadIdx.x;
    if (j >= hdr[0]) return;
    const int h = idx[j];
    const float bv = bias[h];
    float* o = out + ((size_t)b * 512 + h) * (size_t)T;
    const size_t STR = (size_t)128 * 128;    // t-stride in (t,b,j) buffers

    float hs = 0.f, y = 0.f;

    if (jt == 0) {
        const float* p0 = xwp + (size_t)b * 128 + j;
        const float* p1 = p0 + PART;
        const float* p2 = p0 + 2 * PART;
        const float* p3 = p0 + 3 * PART;
        float n0[8], n1[8], n2[8], n3[8];
        #pragma unroll
        for (int d = 0; d < 8; d++) {
            n0[d] = p0[(size_t)d * STR]; n1[d] = p1[(size_t)d * STR];
            n2[d] = p2[(size_t)d * STR]; n3[d] = p3[(size_t)d * STR];
        }
        for (int t0 = 0; t0 < T; t0 += 8) {
            float cur[8], yb[8];
            #pragma unroll
            for (int d = 0; d < 8; d++) cur[d] = (n0[d] + n1[d]) + (n2[d] + n3[d]);
            const bool more = (t0 + 8) < T;
            #pragma unroll
            for (int d = 0; d < 8; d++) {
                size_t off = (size_t)(t0 + 8 + d) * STR;
                n0[d] = more ? p0[off] : 0.f; n1[d] = more ? p1[off] : 0.f;
                n2[d] = more ? p2[off] : 0.f; n3[d] = more ? p3[off] : 0.f;
            }
            #pragma unroll
            for (int d = 0; d < 8; d++) {
                // (1-y) is exactly 0 or 1 -> relu chain matches reference rounding
                hs = fmaf(DECAYF * hs, 1.f - y, cur[d]);
                hs = fmaxf(hs, 0.f);
                y  = (hs + bv > 0.f) ? 1.f : 0.f;
                yb[d] = y;
            }
            *(float4*)(o + t0)     = *(float4*)&yb[0];
            *(float4*)(o + t0 + 4) = *(float4*)&yb[4];
        }
    } else {
        const float* p = xwc1 + (size_t)b * 128 + (j - 128);
        float nx[8];
        #pragma unroll
        for (int d = 0; d < 8; d++) nx[d] = p[(size_t)d * STR];
        for (int t0 = 0; t0 < T; t0 += 8) {
            float cur[8], yb[8];
            #pragma unroll
            for (int d = 0; d < 8; d++) cur[d] = nx[d];
            const bool more = (t0 + 8) < T;
            #pragma unroll
            for (int d = 0; d < 8; d++)
                nx[d] = more ? p[(size_t)(t0 + 8 + d) * STR] : 0.f;
            #pragma unroll
            for (int d = 0; d < 8; d++) {
                hs = fmaf(DECAYF * hs, 1.f - y, cur[d]);
                hs = fmaxf(hs, 0.f);
                y  = (hs + bv > 0.f) ? 1.f : 0.f;
                yb[d] = y;
            }
            *(float4*)(o + t0)     = *(float4*)&yb[0];
            *(float4*)(o + t0 + 4) = *(float4*)&yb[4];
        }
    }
}

extern "C" void kernel_launch(void* const* d_in, const int* in_sizes, int n_in,
                              void* d_out, int out_size, void* d_ws, size_t ws_size,
                              hipStream_t stream) {
    const float* x    = (const float*)d_in[0];  // (128, 512, 512)
    const float* W    = (const float*)d_in[1];  // (512, 512)
    const float* bias = (const float*)d_in[2];  // (1, 512)
    float* out = (float*)d_out;                 // (B,H,T) = (128, 512, 512)

    char* ws = (char*)d_ws;
    int*   hdr  = (int*)(ws + 0);
    int*   idx  = (int*)(ws + 64);
    float* Wc   = (float*)(ws + 4096);
    float* xwp  = (float*)(ws + ((size_t)1 << 20));
    float* xwc1 = (float*)(ws + ((size_t)129 << 20));

    compact_gather<<<1, 512, 0, stream>>>(bias, W, hdr, idx, Wc);
    dim3 g1(5, 4, 128);   // (kc + overflow, t-tiles, B)
    gemm_split<<<g1, 256, 0, stream>>>(x, Wc, hdr, xwp, xwc1);
    fill_ones<<<4096, 256, 0, stream>>>(bias, (float4*)out);
    dim3 g2(128, 2);
    snu_scan<<<g2, 128, 0, stream>>>(xwp, xwc1, bias, hdr, idx, out);
}

// Round 6
// 364.368 us; speedup vs baseline: 1.2757x; 1.2757x over previous
//
#include <hip/hip_runtime.h>

// SNU with bias-sign collapse:
//   y_t = (relu(xw_t + 0.8*h*(1-y)) + b > 0).  relu >= 0, so b_h > 0  =>  y == 1 for all t.
// Only columns with b_h <= 0 (~81 of 512) need the GEMM + sequential scan.
//
// R6: keep split-K x4 gemm (130us, 52% VALU). Fix R5's tail regressions:
//  - compact/gather un-fused (grid gather, not single-block)
//  - reduce4: coalesced in-place sum of the 4 partials into xwp[0]
//  - scan reads ONE (t,b,j) stream, j-fast lanes (wave-coalesced)
//
// ws layout (bytes):
//   0       : int hdr[2] = {count, pc}
//   64      : int idx[256]        compacted h-indices (ascending, padded w/ idx[0])
//   4096    : float Wc[512][256]  gathered W columns (512 KB)
//   1<<20   : float xwp[4][T=512][B=128][128]  4 x 32 MB split-K partials, (t,b,j);
//                                              xwp[0] becomes the reduced sum
//   129<<20 : float xwc1[T=512][B=128][128]    overflow direct buffer (j in [128,256)),
//                                              touched only if count > 128 (P ~ 6e-9)

#define DECAYF 0.8f
#define PART   ((size_t)512 * 128 * 128)   // floats per split-K partial

// ---------- 1. compact: ordered list of columns with b <= 0 ----------
__global__ __launch_bounds__(512) void compact_cols(const float* __restrict__ bias,
                                                    int* __restrict__ hdr,
                                                    int* __restrict__ idx) {
    __shared__ unsigned long long wmask[8];
    const int tid = threadIdx.x;           // 512 threads, H=512
    const bool p = (bias[tid] <= 0.0f);
    unsigned long long m = __ballot(p);
    const int wid = tid >> 6, lane = tid & 63;
    if (lane == 0) wmask[wid] = m;
    __syncthreads();
    int before = 0, total = 0;
    #pragma unroll
    for (int w = 0; w < 8; w++) {
        int c = __popcll(wmask[w]);
        if (w < wid) before += c;
        total += c;
    }
    if (p) idx[before + __popcll(m & ((1ull << lane) - 1ull))] = tid;
    __syncthreads();
    int idx0 = (total > 0) ? idx[0] : 0;
    if (tid >= total && tid < 256) idx[tid] = idx0;     // pad
    if (tid == 0) {
        int pc = (total + 127) & ~127;
        if (pc < 128) pc = 128;
        if (pc > 256) pc = 256;                          // safety clamp (fits ws)
        hdr[0] = total;
        hdr[1] = pc;
    }
}

// ---------- 2. gather Wc[i][j] = W[i][idx[j]] ----------
__global__ __launch_bounds__(256) void gather_W(const float* __restrict__ W,
                                                const int* __restrict__ idx,
                                                float* __restrict__ Wc) {
    const int i = blockIdx.x;            // 512 rows
    const int j = threadIdx.x;           // 256 cols
    Wc[i * 256 + j] = W[i * 512 + idx[j]];
}

// ---------- 3. GEMM: x(B,I,T) x Wc(I,:) -> partials ----------
// grid (5, 4, 128) = (kc, t-tiles, B).  kc<4: split-K chunk of 128 over cols 0..127
// into xwp[kc]. kc==4: overflow path (full K, cols 128..255) -> xwc1; exits if pc<=128.
// 2048 working blocks -> 8/CU, 32 waves/CU. Inner: 8x8/thread, 128x128 tile.
__global__ __launch_bounds__(256) void gemm_split(const float* __restrict__ x,
                                                  const float* __restrict__ Wc,
                                                  const int* __restrict__ hdr,
                                                  float* __restrict__ xwp,
                                                  float* __restrict__ xwc1) {
    const int kc = blockIdx.x;
    int kbeg, kend, coff;
    float* op;
    if (kc < 4) { kbeg = kc * 128; kend = kbeg + 128; coff = 0;   op = xwp + (size_t)kc * PART; }
    else        { if (hdr[1] <= 128) return;
                  kbeg = 0;        kend = 512;        coff = 128; op = xwc1; }
    const int I = 512, T = 512, NC = 256;
    const int b  = blockIdx.z;
    const int t0 = blockIdx.y * 128;

    __shared__ float As[16][132];  // [i][t]
    __shared__ float Bs[16][132];  // [i][j]

    const int tid  = threadIdx.x;
    const int wave = tid >> 6;
    const int lane = tid & 63;
    const int lx = lane & 7;
    const int ly = lane >> 3;
    const int m_base = ((wave >> 1) << 6) + ly * 8;  // t within tile (0..127)
    const int n_base = ((wave & 1) << 6) + lx * 8;   // j within 128 cols

    float acc[8][8];
    #pragma unroll
    for (int i = 0; i < 8; i++)
        #pragma unroll
        for (int j = 0; j < 8; j++) acc[i][j] = 0.f;

    const float* xb = x + (size_t)b * I * T;

    for (int k0 = kbeg; k0 < kend; k0 += 16) {
        #pragma unroll
        for (int j = 0; j < 2; j++) {   // stage 16x128 of A and B: 2 float4/thread each
            int id2 = tid + j * 256;
            int row = id2 >> 5;
            int c4  = (id2 & 31) << 2;
            *(float4*)&As[row][c4] = *(const float4*)(xb + (size_t)(k0 + row) * T + t0 + c4);
            *(float4*)&Bs[row][c4] = *(const float4*)(Wc + (size_t)(k0 + row) * NC + coff + c4);
        }
        __syncthreads();
        #pragma unroll
        for (int kk = 0; kk < 16; kk++) {
            float a[8], bb[8];
            *(float4*)&a[0]  = *(const float4*)&As[kk][m_base];
            *(float4*)&a[4]  = *(const float4*)&As[kk][m_base + 4];
            *(float4*)&bb[0] = *(const float4*)&Bs[kk][n_base];
            *(float4*)&bb[4] = *(const float4*)&Bs[kk][n_base + 4];
            #pragma unroll
            for (int mi = 0; mi < 8; mi++)
                #pragma unroll
                for (int ni = 0; ni < 8; ni++)
                    acc[mi][ni] = fmaf(a[mi], bb[ni], acc[mi][ni]);
        }
        __syncthreads();
    }

    // store (t,b,j) layout: per t, a wave covers 8 x 32B contiguous runs
    #pragma unroll
    for (int mi = 0; mi < 8; mi++) {
        int t = t0 + m_base + mi;
        float* o = op + ((size_t)t * 128 + b) * 128 + n_base;
        *(float4*)o       = *(float4*)&acc[mi][0];
        *(float4*)(o + 4) = *(float4*)&acc[mi][4];
    }
}

// ---------- 4. reduce: xwp[0] += xwp[1..3], fully coalesced, in place ----------
// Each element owned by exactly one thread (read-then-write same index): race-free.
// Sum order (p0+p1)+(p2+p3) matches R5's verified inline order bit-for-bit.
__global__ __launch_bounds__(256) void reduce4(float4* __restrict__ xwp4) {
    const size_t P4 = PART / 4;              // float4s per partial
    const size_t base = (size_t)blockIdx.x * 1024 + threadIdx.x;
    #pragma unroll
    for (int q = 0; q < 4; q++) {
        size_t i = base + (size_t)q * 256;   // grid 2048*1024 covers P4 exactly
        float4 a = xwp4[i], b = xwp4[i + P4], c = xwp4[i + 2 * P4], d = xwp4[i + 3 * P4];
        float4 r;
        r.x = (a.x + b.x) + (c.x + d.x);
        r.y = (a.y + b.y) + (c.y + d.y);
        r.z = (a.z + b.z) + (c.z + d.z);
        r.w = (a.w + b.w) + (c.w + d.w);
        xwp4[i] = r;
    }
}

// ---------- 5. ones-fill: rows with bias > 0 are all-ones ----------
__global__ __launch_bounds__(256) void fill_ones(const float* __restrict__ bias,
                                                 float4* __restrict__ out4) {
    const float4 ones = make_float4(1.f, 1.f, 1.f, 1.f);
    const int base = blockIdx.x * 2048;
    #pragma unroll
    for (int q = 0; q < 8; q++) {
        int f4 = base + q * 256 + threadIdx.x;   // (B,H,T): 128 float4 per h-row
        int h = (f4 >> 7) & 511;
        if (bias[h] > 0.0f) out4[f4] = ones;
    }
}

// ---------- 6. scan: single reduced stream, run recurrence, write spikes ----------
// grid (128 b, 2 jt) x 128 threads. jt=0: j<128 from xwp[0]; jt=1: overflow from xwc1.
// Reads: j-fast lanes -> 256B contiguous per wave-load; 8-t register lookahead.
__global__ __launch_bounds__(128) void snu_scan(const float* __restrict__ xwp,
                                                const float* __restrict__ xwc1,
                                                const float* __restrict__ bias,
                                                const int* __restrict__ hdr,
                                                const int* __restrict__ idx,
                                                float* __restrict__ out) {
    const int T = 512;
    const int b  = blockIdx.x;
    const int jt = blockIdx.y;
    const int j  = jt * 128 + threadIdx.x;
    if (j >= hdr[0]) return;
    const int h = idx[j];
    const float bv = bias[h];
    float* o = out + ((size_t)b * 512 + h) * (size_t)T;
    const size_t STR = (size_t)128 * 128;    // t-stride in (t,b,j) buffers

    const float* p = (jt == 0) ? (xwp + (size_t)b * 128 + j)
                               : (xwc1 + (size_t)b * 128 + (j - 128));

    float hs = 0.f, y = 0.f;
    float nx[8];
    #pragma unroll
    for (int d = 0; d < 8; d++) nx[d] = p[(size_t)d * STR];

    for (int t0 = 0; t0 < T; t0 += 8) {
        float cur[8], yb[8];
        #pragma unroll
        for (int d = 0; d < 8; d++) cur[d] = nx[d];
        const bool more = (t0 + 8) < T;
        #pragma unroll
        for (int d = 0; d < 8; d++)
            nx[d] = more ? p[(size_t)(t0 + 8 + d) * STR] : 0.f;
        #pragma unroll
        for (int d = 0; d < 8; d++) {
            // (1-y) is exactly 0 or 1 -> relu chain matches reference rounding
            hs = fmaf(DECAYF * hs, 1.f - y, cur[d]);
            hs = fmaxf(hs, 0.f);
            y  = (hs + bv > 0.f) ? 1.f : 0.f;
            yb[d] = y;
        }
        *(float4*)(o + t0)     = *(float4*)&yb[0];
        *(float4*)(o + t0 + 4) = *(float4*)&yb[4];
    }
}

extern "C" void kernel_launch(void* const* d_in, const int* in_sizes, int n_in,
                              void* d_out, int out_size, void* d_ws, size_t ws_size,
                              hipStream_t stream) {
    const float* x    = (const float*)d_in[0];  // (128, 512, 512)
    const float* W    = (const float*)d_in[1];  // (512, 512)
    const float* bias = (const float*)d_in[2];  // (1, 512)
    float* out = (float*)d_out;                 // (B,H,T) = (128, 512, 512)

    char* ws = (char*)d_ws;
    int*   hdr  = (int*)(ws + 0);
    int*   idx  = (int*)(ws + 64);
    float* Wc   = (float*)(ws + 4096);
    float* xwp  = (float*)(ws + ((size_t)1 << 20));
    float* xwc1 = (float*)(ws + ((size_t)129 << 20));

    compact_cols<<<1, 512, 0, stream>>>(bias, hdr, idx);
    gather_W<<<512, 256, 0, stream>>>(W, idx, Wc);
    dim3 g1(5, 4, 128);   // (kc + overflow, t-tiles, B)
    gemm_split<<<g1, 256, 0, stream>>>(x, Wc, hdr, xwp, xwc1);
    reduce4<<<2048, 256, 0, stream>>>((float4*)xwp);
    fill_ones<<<4096, 256, 0, stream>>>(bias, (float4*)out);
    dim3 g2(128, 2);
    snu_scan<<<g2, 128, 0, stream>>>(xwp, xwc1, bias, hdr, idx, out);
}